// Round 7
// baseline (131847.620 us; speedup 1.0000x reference)
//
#include <hip/hip_runtime.h>

#define T_STEPS 65536
#define IN_DIM 5
#define H1 26
#define H2 121

typedef __attribute__((ext_vector_type(2))) float f32x2;
typedef __attribute__((ext_vector_type(4))) float f32x4;

__device__ __forceinline__ float fsig(float x) {
    float e = __builtin_amdgcn_exp2f(-1.44269504f * x);
    return __builtin_amdgcn_rcpf(1.0f + e);
}
__device__ __forceinline__ float ftanh(float x) {
    float e = __builtin_amdgcn_exp2f(2.88539008f * x);
    return 1.0f - 2.0f * __builtin_amdgcn_rcpf(e + 1.0f);
}
__device__ __forceinline__ f32x2 mk2(float a, float b) { f32x2 r; r[0] = a; r[1] = b; return r; }
// packed fp32 FMA: acc.lo += a.lo*b.lo, acc.hi += a.hi*b.hi (IEEE FMA per lane)
__device__ __forceinline__ void pk(f32x2& acc, f32x2 a, f32x2 b) {
    asm("v_pk_fma_f32 %0, %1, %2, %0" : "+v"(acc) : "v"(a), "v"(b));
}
#define PIN(a) asm volatile("" : "+v"(a));

// ---- LDS partition (floats) ----
// ldsA: W_hh2 tail k=56..120 per row, stride 68 (j=65..67 zero pad): 484*68 = 32912
// ldsB: W_hh1 per unit l: 4 gates * 28 (k=26,27 pad unread):          26*112 =  2912
// h1a/h1b (double buffer, pads 26..31 zero), h2s (pads 121..127 zero), g2w, yp
#define A_OFF   0
#define B_OFF   32912
#define H1A_OFF 35824
#define H1B_OFF 35856
#define H2_OFF  35888
#define G2_OFF  36016
#define YP_OFF  36500
#define LDS_FLOATS 36502
#define LDS_BYTES (LDS_FLOATS * 4)

// 1024 threads = 16 waves = 4 waves/EU.
// Roles: g2 rows (2 thr/row): tid 0..127 -> rows 0..63; tid 160..999 -> rows 64..483.
//        LSTM1: tid 128..153 (unit l = tid-128), runs in the ACT region (computes
//               h1(t+1) overlapped with h2(t) activation; h1 double-buffered).
//        y-store: tid 154 (in the A+C region, reads ypart of step t-1).
// Per-g2-thread weights: k = half*28+0..27 of W_hh2 row in 14 f32x2 REGISTERS,
// k = 56+half*32+0..31 (+120) streamed from LDS; W_ih2 half-row (14/12) in regs.
// All hot-loop MACs via v_pk_fma_f32 onto independent packed accumulators.
__global__ __attribute__((amdgpu_flat_work_group_size(1024, 1024)))
__attribute__((amdgpu_waves_per_eu(4, 4)))
void lstm_seq_kernel(
    const float* __restrict__ x,
    const float* __restrict__ W_ih1, const float* __restrict__ W_hh1,
    const float* __restrict__ b_ih1, const float* __restrict__ b_hh1,
    const float* __restrict__ W_ih2, const float* __restrict__ W_hh2,
    const float* __restrict__ b_ih2, const float* __restrict__ b_hh2,
    const float* __restrict__ W_lin, const float* __restrict__ b_lin,
    const float* __restrict__ h1_0, const float* __restrict__ c1_0,
    const float* __restrict__ h2_0, const float* __restrict__ c2_0,
    float* __restrict__ out)
{
    extern __shared__ float smem[];
    float* ldsA = smem + A_OFF;
    float* ldsB = smem + B_OFF;
    float* h1a  = smem + H1A_OFF;
    float* h1b  = smem + H1B_OFF;
    float* h2s  = smem + H2_OFF;
    float* g2w  = smem + G2_OFF;
    float* yp   = smem + YP_OFF;

    const int tid = threadIdx.x;
    const bool is_g2 = (tid < 128) || (tid >= 160 && tid < 1000);
    const int  l     = tid - 128;                 // LSTM1 unit when 0<=l<26
    const bool is_l1 = ((unsigned)l < 26u);
    const int  gtid  = (tid < 128) ? tid : (tid - 32);
    const int  row   = gtid >> 1;
    const int  half  = gtid & 1;

    // ---------------- staging: weights -> LDS (one-time) ----------------
    for (int i = tid; i < 484 * 68; i += 1024) {
        int r = i / 68, j = i - r * 68;
        ldsA[i] = (j < 65) ? W_hh2[r * H2 + 56 + j] : 0.0f;
    }
    for (int i = tid; i < 104 * 26; i += 1024) {
        int R = i / 26, k = i - R * 26;
        int g = R / 26, u = R - g * 26;
        ldsB[u * 112 + g * 28 + k] = W_hh1[R * 26 + k];
    }
    if (tid < 32) { h1a[tid] = 0.0f; h1b[tid] = 0.0f; }
    if (tid >= 32 && tid < 160) { int j = tid - 32; h2s[j] = (j < H2) ? h2_0[j] : 0.0f; }

    // ---------------- per-role register init ----------------
    f32x2 W0{},W1{},W2{},W3{},W4{},W5{},W6{},W7{},W8{},W9{},W10{},W11{},W12{},W13{};
    f32x2 U0{},U1{},U2{},U3{},U4{},U5{},U6{};
    float bias = 0.0f, c2 = 0.0f, wlin = 0.0f;
    f32x2 V00{},V01{},V10{},V11{},V20{},V21{},V30{},V31{};
    float s0=0,s1=0,s2=0,s3=0, b0=0,b1=0,b2=0,b3=0, c1=0;
    f32x2 px01{}, px23{}; float px4 = 0.0f;

    if (is_g2) {
        const float* wp = W_hh2 + row * H2 + half * 28;
        W0=mk2(wp[0],wp[1]);   W1=mk2(wp[2],wp[3]);   W2=mk2(wp[4],wp[5]);   W3=mk2(wp[6],wp[7]);
        W4=mk2(wp[8],wp[9]);   W5=mk2(wp[10],wp[11]); W6=mk2(wp[12],wp[13]); W7=mk2(wp[14],wp[15]);
        W8=mk2(wp[16],wp[17]); W9=mk2(wp[18],wp[19]); W10=mk2(wp[20],wp[21]);W11=mk2(wp[22],wp[23]);
        W12=mk2(wp[24],wp[25]);W13=mk2(wp[26],wp[27]);
        const float* up = W_ih2 + row * H1 + half * 14;
        U0=mk2(up[0],up[1]); U1=mk2(up[2],up[3]); U2=mk2(up[4],up[5]);
        U3=mk2(up[6],up[7]); U4=mk2(up[8],up[9]); U5=mk2(up[10],up[11]);
        U6 = half ? mk2(0.0f,0.0f) : mk2(up[12],up[13]);
        bias = half ? 0.0f : (b_ih2[row] + b_hh2[row]);
        PIN(W0) PIN(W1) PIN(W2) PIN(W3) PIN(W4) PIN(W5) PIN(W6) PIN(W7)
        PIN(W8) PIN(W9) PIN(W10) PIN(W11) PIN(W12) PIN(W13)
        PIN(U0) PIN(U1) PIN(U2) PIN(U3) PIN(U4) PIN(U5) PIN(U6) PIN(bias)
    } else if (is_l1) {
        const float* q0 = W_ih1 + (0 * 26 + l) * IN_DIM;
        const float* q1 = W_ih1 + (1 * 26 + l) * IN_DIM;
        const float* q2 = W_ih1 + (2 * 26 + l) * IN_DIM;
        const float* q3 = W_ih1 + (3 * 26 + l) * IN_DIM;
        V00=mk2(q0[0],q0[1]); V01=mk2(q0[2],q0[3]); s0=q0[4];
        V10=mk2(q1[0],q1[1]); V11=mk2(q1[2],q1[3]); s1=q1[4];
        V20=mk2(q2[0],q2[1]); V21=mk2(q2[2],q2[3]); s2=q2[4];
        V30=mk2(q3[0],q3[1]); V31=mk2(q3[2],q3[3]); s3=q3[4];
        b0 = b_ih1[l]      + b_hh1[l];
        b1 = b_ih1[26 + l] + b_hh1[26 + l];
        b2 = b_ih1[52 + l] + b_hh1[52 + l];
        b3 = b_ih1[78 + l] + b_hh1[78 + l];
        c1 = c1_0[l];
        PIN(V00) PIN(V01) PIN(V10) PIN(V11) PIN(V20) PIN(V21) PIN(V30) PIN(V31)
    }
    if (tid < H2) { c2 = c2_0[tid]; wlin = W_lin[tid]; PIN(c2) PIN(wlin) }
    const float blin = b_lin[0];

    __syncthreads();   // staging complete

    // ---------------- prologue: LSTM1 computes h1(0) into h1a ----------------
    if (is_l1) {
        float xa0 = x[0], xa1 = x[1], xa2 = x[2], xa3 = x[3], xa4 = x[4];
        float gg0, gg1, gg2, gg3;
#define PRO(g, DEST, Va, Vb, ss, bb) { \
        float a = bb; const float* wr = ldsB + l * 112 + g * 28; \
        _Pragma("unroll") \
        for (int k = 0; k < 26; ++k) a = fmaf(wr[k], h1_0[k], a); \
        a = fmaf(Va[0], xa0, a); a = fmaf(Va[1], xa1, a); \
        a = fmaf(Vb[0], xa2, a); a = fmaf(Vb[1], xa3, a); \
        a = fmaf(ss, xa4, a); DEST = a; }
        PRO(0, gg0, V00, V01, s0, b0)
        PRO(1, gg1, V10, V11, s1, b1)
        PRO(2, gg2, V20, V21, s2, b2)
        PRO(3, gg3, V30, V31, s3, b3)
        c1 = fsig(gg1) * c1 + fsig(gg0) * ftanh(gg2);
        h1a[l] = fsig(gg3) * ftanh(c1);
    }
    __syncthreads();   // h1(0) visible

    // loop-invariant pointers
    const f32x4* hA4 = (const f32x4*)h2s + half * 7;        // reg-part h2 chunks
    const f32x4* hL4 = (const f32x4*)h2s + 14 + half * 8;   // lds-part h2 chunks
    const f32x4* wL4 = (const f32x4*)ldsA + row * 17 + half * 8;
    const int toff  = row * 68 + 64 + ((half ^ 1) << 1);    // k=120 tail (or pad)
    const int thoff = 120 + (half ^ 1);
    const int H7 = half * 7;
    const f32x4* wb4 = (const f32x4*)ldsB + l * 28;         // LSTM1 W_hh1 chunks
    const f32x2* wb2 = (const f32x2*)ldsB + l * 56;
    const f32x2* h1rd = (const f32x2*)h1a;
    float*       h1wr = h1b;

    for (int t = 0; t < T_STEPS; ++t) {
        // ---------- Region 1: gates2 = W_hh2@h2(t-1) + W_ih2@h1(t) + b ----------
        if (is_g2) {
            f32x2 a01 = mk2(bias, 0.0f), a23 = mk2(0.0f, 0.0f);
            f32x2 a45 = mk2(0.0f, 0.0f), a67 = mk2(0.0f, 0.0f);
#define PHR(q, Wa, Wb) { f32x4 hv = hA4[q]; \
            pk(a01, Wa, mk2(hv[0], hv[1])); pk(a23, Wb, mk2(hv[2], hv[3])); }
            PHR(0, W0, W1)  PHR(1, W2, W3)  PHR(2, W4, W5)  PHR(3, W6, W7)
            PHR(4, W8, W9)  PHR(5, W10, W11) PHR(6, W12, W13)
#define PHL(q) { f32x4 wv = wL4[q]; f32x4 hv = hL4[q]; \
            pk(a45, mk2(wv[0], wv[1]), mk2(hv[0], hv[1])); \
            pk(a67, mk2(wv[2], wv[3]), mk2(hv[2], hv[3])); }
            PHL(0) PHL(1) PHL(2) PHL(3) PHL(4) PHL(5) PHL(6) PHL(7)
            float accS = ldsA[toff] * h2s[thoff];           // k=120 (half1) / 0 (half0)
#define PHC(q, Uu) pk(a01, Uu, h1rd[H7 + q]);
            PHC(0, U0) PHC(1, U1) PHC(2, U2) PHC(3, U3) PHC(4, U4) PHC(5, U5) PHC(6, U6)
            float r = (a01[0] + a01[1]) + (a23[0] + a23[1])
                    + (a45[0] + a45[1]) + (a67[0] + a67[1]) + accS;
            r += __shfl_xor(r, 1);
            if (!half) g2w[row] = r;
        } else if (is_l1) {
            // prefetch x(t+1) (used in Region 2)
            int tn = t + 1; if (tn >= T_STEPS) tn = T_STEPS - 1;
            const float* xp = x + tn * IN_DIM;
            px01 = mk2(xp[0], xp[1]); px23 = mk2(xp[2], xp[3]); px4 = xp[4];
        } else if (tid == 154) {
            if (t > 0) out[t - 1] = yp[0] + yp[1] + blin;
        }
        __syncthreads();   // B2: gates2 visible

        // ---------- Region 2: h2/c2 activation (+y) || LSTM1 -> h1(t+1) ----------
        if (tid < 128) {
            float p = 0.0f;
            if (tid < H2) {
                float gi = g2w[tid];
                float gf = g2w[121 + tid];
                float gg = g2w[242 + tid];
                float go = g2w[363 + tid];
                c2 = fsig(gf) * c2 + fsig(gi) * ftanh(gg);
                float h2n = fsig(go) * ftanh(c2);
                h2s[tid] = h2n;
                p = h2n * wlin;
            }
            #pragma unroll
            for (int off = 32; off >= 1; off >>= 1) p += __shfl_xor(p, off);
            if ((tid & 63) == 0) yp[tid >> 6] = p;
        } else if (is_l1) {
            f32x2 A0 = mk2(b0, 0.0f), A1 = mk2(b1, 0.0f);
            f32x2 A2 = mk2(b2, 0.0f), A3 = mk2(b3, 0.0f);
            pk(A0, V00, px01); pk(A0, V01, px23);
            pk(A1, V10, px01); pk(A1, V11, px23);
            pk(A2, V20, px01); pk(A2, V21, px23);
            pk(A3, V30, px01); pk(A3, V31, px23);
#define GH(A, base4, base2) { \
            f32x4 w_; \
            w_ = wb4[(base4) + 0]; pk(A, mk2(w_[0],w_[1]), h1rd[0]);  pk(A, mk2(w_[2],w_[3]), h1rd[1]); \
            w_ = wb4[(base4) + 1]; pk(A, mk2(w_[0],w_[1]), h1rd[2]);  pk(A, mk2(w_[2],w_[3]), h1rd[3]); \
            w_ = wb4[(base4) + 2]; pk(A, mk2(w_[0],w_[1]), h1rd[4]);  pk(A, mk2(w_[2],w_[3]), h1rd[5]); \
            w_ = wb4[(base4) + 3]; pk(A, mk2(w_[0],w_[1]), h1rd[6]);  pk(A, mk2(w_[2],w_[3]), h1rd[7]); \
            w_ = wb4[(base4) + 4]; pk(A, mk2(w_[0],w_[1]), h1rd[8]);  pk(A, mk2(w_[2],w_[3]), h1rd[9]); \
            w_ = wb4[(base4) + 5]; pk(A, mk2(w_[0],w_[1]), h1rd[10]); pk(A, mk2(w_[2],w_[3]), h1rd[11]); \
            { f32x2 wt = wb2[(base2) + 12]; pk(A, wt, h1rd[12]); } }
            GH(A0, 0,  0)  GH(A1, 7,  14)  GH(A2, 14, 28)  GH(A3, 21, 42)
            float g0v = fmaf(s0, px4, A0[0] + A0[1]);
            float g1v = fmaf(s1, px4, A1[0] + A1[1]);
            float g2v = fmaf(s2, px4, A2[0] + A2[1]);
            float g3v = fmaf(s3, px4, A3[0] + A3[1]);
            c1 = fsig(g1v) * c1 + fsig(g0v) * ftanh(g2v);
            h1wr[l] = fsig(g3v) * ftanh(c1);
        }
        __syncthreads();   // B3: h2(t), ypart, h1(t+1) visible

        { const f32x2* tr = h1rd; h1rd = (const f32x2*)h1wr; h1wr = (float*)tr; }
    }

    if (tid == 154) out[T_STEPS - 1] = yp[0] + yp[1] + blin;
}

extern "C" void kernel_launch(void* const* d_in, const int* in_sizes, int n_in,
                              void* d_out, int out_size, void* d_ws, size_t ws_size,
                              hipStream_t stream) {
    const float* x     = (const float*)d_in[0];
    const float* W_ih1 = (const float*)d_in[1];
    const float* W_hh1 = (const float*)d_in[2];
    const float* b_ih1 = (const float*)d_in[3];
    const float* b_hh1 = (const float*)d_in[4];
    const float* W_ih2 = (const float*)d_in[5];
    const float* W_hh2 = (const float*)d_in[6];
    const float* b_ih2 = (const float*)d_in[7];
    const float* b_hh2 = (const float*)d_in[8];
    const float* W_lin = (const float*)d_in[9];
    const float* b_lin = (const float*)d_in[10];
    const float* h1_0  = (const float*)d_in[11];
    const float* c1_0  = (const float*)d_in[12];
    const float* h2_0  = (const float*)d_in[13];
    const float* c2_0  = (const float*)d_in[14];
    float* out = (float*)d_out;

    (void)hipFuncSetAttribute((const void*)lstm_seq_kernel,
                              hipFuncAttributeMaxDynamicSharedMemorySize, LDS_BYTES);
    hipLaunchKernelGGL(lstm_seq_kernel, dim3(1), dim3(1024), LDS_BYTES, stream,
                       x, W_ih1, W_hh1, b_ih1, b_hh1,
                       W_ih2, W_hh2, b_ih2, b_hh2,
                       W_lin, b_lin, h1_0, c1_0, h2_0, c2_0, out);
}

// Round 8
// 84431.061 us; speedup vs baseline: 1.5616x; 1.5616x over previous
//
#include <hip/hip_runtime.h>
#include <hip/hip_fp16.h>

#define T_STEPS 65536
#define IN_DIM 5
#define H1 26
#define H2 121

__device__ __forceinline__ float fsig(float x) {
    float e = __builtin_amdgcn_exp2f(-1.44269504f * x);
    return __builtin_amdgcn_rcpf(1.0f + e);
}
__device__ __forceinline__ float ftanh(float x) {
    float e = __builtin_amdgcn_exp2f(2.88539008f * x);
    return 1.0f - 2.0f * __builtin_amdgcn_rcpf(e + 1.0f);
}
__device__ __forceinline__ uint32_t pk2h(float lo, float hi) {
    unsigned short ul = __half_as_ushort(__float2half(lo));
    unsigned short uh = __half_as_ushort(__float2half(hi));
    return ((uint32_t)uh << 16) | ul;
}

// mixed-precision FMA: acc(f32) += f16(a) * f16(b); lo/hi half selected
#define MIX_LO(acc, a, b) asm("v_fma_mix_f32 %0, %1, %2, %0 op_sel:[0,0,0] op_sel_hi:[1,1,0]" : "+v"(acc) : "v"(a), "v"(b));
#define MIX_HI(acc, a, b) asm("v_fma_mix_f32 %0, %1, %2, %0 op_sel:[1,1,0] op_sel_hi:[1,1,0]" : "+v"(acc) : "v"(a), "v"(b));
#define PIN(a) asm volatile("" : "+v"(a));
#define SB() __builtin_amdgcn_sched_barrier(0)

#define FORW61(F) F(0) F(1) F(2) F(3) F(4) F(5) F(6) F(7) F(8) F(9) F(10) F(11) F(12) F(13) F(14) F(15) \
 F(16) F(17) F(18) F(19) F(20) F(21) F(22) F(23) F(24) F(25) F(26) F(27) F(28) F(29) F(30) F(31) \
 F(32) F(33) F(34) F(35) F(36) F(37) F(38) F(39) F(40) F(41) F(42) F(43) F(44) F(45) F(46) F(47) \
 F(48) F(49) F(50) F(51) F(52) F(53) F(54) F(55) F(56) F(57) F(58) F(59) F(60)
#define FOR13(F) F(0) F(1) F(2) F(3) F(4) F(5) F(6) F(7) F(8) F(9) F(10) F(11) F(12)

// 512 threads = 8 waves = 2 waves/SIMD (R6 geometry -> observed VGPR grant 96).
// All matvec operands fp16: weights packed in VGPRs (61+13 regs, fits grant),
// h2/h1 broadcast from LDS as f16 (16+4 ds_read_b128/wave vs R6's 38).
// tid 0..483  : gates2 row r=tid (region1); tid<121 also act role (region2)
// tid 484..509: LSTM1 unit l=tid-484 (region2; x-prefetch in region1)
// tid 510     : y-store of step t-1 (region1)
__global__ __attribute__((amdgpu_flat_work_group_size(512, 512)))
__attribute__((amdgpu_waves_per_eu(2, 2)))
void lstm_seq_kernel(
    const float* __restrict__ x,
    const float* __restrict__ W_ih1, const float* __restrict__ W_hh1,
    const float* __restrict__ b_ih1, const float* __restrict__ b_hh1,
    const float* __restrict__ W_ih2, const float* __restrict__ W_hh2,
    const float* __restrict__ b_ih2, const float* __restrict__ b_hh2,
    const float* __restrict__ W_lin, const float* __restrict__ b_lin,
    const float* __restrict__ h1_0, const float* __restrict__ c1_0,
    const float* __restrict__ h2_0, const float* __restrict__ c2_0,
    float* __restrict__ out)
{
    __shared__ __align__(16) unsigned short h2f16[128];  // h2(t) fp16, pad 121..127 = 0
    __shared__ __align__(16) unsigned short h1f16[32];   // h1(t) fp16, pad 26..31 = 0
    __shared__ float g2w[484];
    __shared__ float yp[2];

    const int tid = threadIdx.x;
    const bool is_g2 = (tid < 484);
    const int  l     = tid - 484;
    const bool is_l1 = ((unsigned)l < 26u);

    // ---------------- packed-f16 weight registers ----------------
#define DECW(i) uint32_t w##i = 0;
    FORW61(DECW)
#define DECU(i) uint32_t u##i = 0;
    FOR13(DECU)
    // LSTM1: 4 gates x 13 hh-pairs, 4 gates x 3 ih-pairs
#define DECK(i) uint32_t k0_##i = 0, k1_##i = 0, k2_##i = 0, k3_##i = 0;
    FOR13(DECK)
    uint32_t i0_0=0,i0_1=0,i0_2=0, i1_0=0,i1_1=0,i1_2=0;
    uint32_t i2_0=0,i2_1=0,i2_2=0, i3_0=0,i3_1=0,i3_2=0;
    float bias = 0.0f, c2 = 0.0f, wlin = 0.0f;
    float bb0=0, bb1=0, bb2=0, bb3=0, c1 = 0.0f;
    uint32_t px01 = 0, px23 = 0, px4r = 0;

    if (is_g2) {
        const float* wp = W_hh2 + tid * H2;
#define PKW(i) w##i = pk2h(wp[2*(i)], wp[2*(i)+1]);
        PKW(0) PKW(1) PKW(2) PKW(3) PKW(4) PKW(5) PKW(6) PKW(7) PKW(8) PKW(9)
        PKW(10) PKW(11) PKW(12) PKW(13) PKW(14) PKW(15) PKW(16) PKW(17) PKW(18) PKW(19)
        PKW(20) PKW(21) PKW(22) PKW(23) PKW(24) PKW(25) PKW(26) PKW(27) PKW(28) PKW(29)
        PKW(30) PKW(31) PKW(32) PKW(33) PKW(34) PKW(35) PKW(36) PKW(37) PKW(38) PKW(39)
        PKW(40) PKW(41) PKW(42) PKW(43) PKW(44) PKW(45) PKW(46) PKW(47) PKW(48) PKW(49)
        PKW(50) PKW(51) PKW(52) PKW(53) PKW(54) PKW(55) PKW(56) PKW(57) PKW(58) PKW(59)
        w60 = pk2h(wp[120], 0.0f);
        const float* up = W_ih2 + tid * H1;
#define PKU(i) u##i = pk2h(up[2*(i)], up[2*(i)+1]);
        FOR13(PKU)
        bias = b_ih2[tid] + b_hh2[tid];
#define PINW(i) PIN(w##i)
        FORW61(PINW)
#define PINU(i) PIN(u##i)
        FOR13(PINU)
        PIN(bias)
    } else if (is_l1) {
        const float* p0 = W_hh1 + (0 * 26 + l) * H1;
        const float* p1 = W_hh1 + (1 * 26 + l) * H1;
        const float* p2 = W_hh1 + (2 * 26 + l) * H1;
        const float* p3 = W_hh1 + (3 * 26 + l) * H1;
#define PKK(i) k0_##i = pk2h(p0[2*(i)], p0[2*(i)+1]); k1_##i = pk2h(p1[2*(i)], p1[2*(i)+1]); \
               k2_##i = pk2h(p2[2*(i)], p2[2*(i)+1]); k3_##i = pk2h(p3[2*(i)], p3[2*(i)+1]);
        FOR13(PKK)
        const float* q0 = W_ih1 + (0 * 26 + l) * IN_DIM;
        const float* q1 = W_ih1 + (1 * 26 + l) * IN_DIM;
        const float* q2 = W_ih1 + (2 * 26 + l) * IN_DIM;
        const float* q3 = W_ih1 + (3 * 26 + l) * IN_DIM;
        i0_0 = pk2h(q0[0], q0[1]); i0_1 = pk2h(q0[2], q0[3]); i0_2 = pk2h(q0[4], 0.0f);
        i1_0 = pk2h(q1[0], q1[1]); i1_1 = pk2h(q1[2], q1[3]); i1_2 = pk2h(q1[4], 0.0f);
        i2_0 = pk2h(q2[0], q2[1]); i2_1 = pk2h(q2[2], q2[3]); i2_2 = pk2h(q2[4], 0.0f);
        i3_0 = pk2h(q3[0], q3[1]); i3_1 = pk2h(q3[2], q3[3]); i3_2 = pk2h(q3[4], 0.0f);
        bb0 = b_ih1[l]      + b_hh1[l];
        bb1 = b_ih1[26 + l] + b_hh1[26 + l];
        bb2 = b_ih1[52 + l] + b_hh1[52 + l];
        bb3 = b_ih1[78 + l] + b_hh1[78 + l];
        c1  = c1_0[l];
        px01 = pk2h(x[0], x[1]); px23 = pk2h(x[2], x[3]); px4r = pk2h(x[4], 0.0f);
#define PINK(i) PIN(k0_##i) PIN(k1_##i) PIN(k2_##i) PIN(k3_##i)
        FOR13(PINK)
        PIN(i0_0) PIN(i0_1) PIN(i0_2) PIN(i1_0) PIN(i1_1) PIN(i1_2)
        PIN(i2_0) PIN(i2_1) PIN(i2_2) PIN(i3_0) PIN(i3_1) PIN(i3_2)
        PIN(bb0) PIN(bb1) PIN(bb2) PIN(bb3)
    }
    if (tid < H2) { c2 = c2_0[tid]; wlin = W_lin[tid]; PIN(c2) PIN(wlin) }
    const float blin = b_lin[0];

    if (tid < 32)  h1f16[tid] = (tid < H1) ? __half_as_ushort(__float2half(h1_0[tid])) : (unsigned short)0;
    if (tid >= 32 && tid < 160) {
        int j = tid - 32;
        h2f16[j] = (j < H2) ? __half_as_ushort(__float2half(h2_0[j])) : (unsigned short)0;
    }
    __syncthreads();

    // LSTM1 step macro: gates from h1f16 (broadcast) + packed x; updates c1, h1f16[l]
#define L1_STEP() { \
        const uint4* Hc = (const uint4*)h1f16; \
        uint4 hc0 = Hc[0], hc1 = Hc[1], hc2 = Hc[2], hc3 = Hc[3]; \
        float A0 = bb0, A1 = bb1, A2 = bb2, A3 = bb3; \
        MIX_LO(A0, i0_0, px01) MIX_HI(A0, i0_0, px01) MIX_LO(A0, i0_1, px23) MIX_HI(A0, i0_1, px23) MIX_LO(A0, i0_2, px4r) \
        MIX_LO(A1, i1_0, px01) MIX_HI(A1, i1_0, px01) MIX_LO(A1, i1_1, px23) MIX_HI(A1, i1_1, px23) MIX_LO(A1, i1_2, px4r) \
        MIX_LO(A2, i2_0, px01) MIX_HI(A2, i2_0, px01) MIX_LO(A2, i2_1, px23) MIX_HI(A2, i2_1, px23) MIX_LO(A2, i2_2, px4r) \
        MIX_LO(A3, i3_0, px01) MIX_HI(A3, i3_0, px01) MIX_LO(A3, i3_1, px23) MIX_HI(A3, i3_1, px23) MIX_LO(A3, i3_2, px4r) \
        GATE(A0, k0_) GATE(A1, k1_) GATE(A2, k2_) GATE(A3, k3_) \
        c1 = fsig(A1) * c1 + fsig(A0) * ftanh(A2); \
        h1f16[l] = __half_as_ushort(__float2half(fsig(A3) * ftanh(c1))); }
#define GATE(A, K) \
        MIX_LO(A, K##0, hc0.x) MIX_HI(A, K##0, hc0.x) MIX_LO(A, K##1, hc0.y) MIX_HI(A, K##1, hc0.y) \
        MIX_LO(A, K##2, hc0.z) MIX_HI(A, K##2, hc0.z) MIX_LO(A, K##3, hc0.w) MIX_HI(A, K##3, hc0.w) \
        MIX_LO(A, K##4, hc1.x) MIX_HI(A, K##4, hc1.x) MIX_LO(A, K##5, hc1.y) MIX_HI(A, K##5, hc1.y) \
        MIX_LO(A, K##6, hc1.z) MIX_HI(A, K##6, hc1.z) MIX_LO(A, K##7, hc1.w) MIX_HI(A, K##7, hc1.w) \
        MIX_LO(A, K##8, hc2.x) MIX_HI(A, K##8, hc2.x) MIX_LO(A, K##9, hc2.y) MIX_HI(A, K##9, hc2.y) \
        MIX_LO(A, K##10, hc2.z) MIX_HI(A, K##10, hc2.z) MIX_LO(A, K##11, hc2.w) MIX_HI(A, K##11, hc2.w) \
        MIX_LO(A, K##12, hc3.x) MIX_HI(A, K##12, hc3.x)

    // prologue: h1(0) from x(0), h1_0, c1_0
    if (is_l1) { L1_STEP() }
    __syncthreads();

    for (int t = 0; t < T_STEPS; ++t) {
        // -------- Region 1: gates2 = W_hh2@h2(t-1) + W_ih2@h1(t) + b --------
        if (is_g2) {
            const uint4* Hh = (const uint4*)h2f16;
            const uint4* Hl = (const uint4*)h1f16;
            float a0 = bias, a1 = 0.0f, a2 = 0.0f, a3 = 0.0f;
            uint4 h;
#define CH(WA, WB, WC, WD) \
            MIX_LO(a0, WA, h.x) MIX_HI(a1, WA, h.x) MIX_LO(a2, WB, h.y) MIX_HI(a3, WB, h.y) \
            MIX_LO(a0, WC, h.z) MIX_HI(a1, WC, h.z) MIX_LO(a2, WD, h.w) MIX_HI(a3, WD, h.w)
            h = Hh[0];  CH(w0,  w1,  w2,  w3)
            h = Hh[1];  CH(w4,  w5,  w6,  w7)
            h = Hh[2];  CH(w8,  w9,  w10, w11)
            h = Hh[3];  CH(w12, w13, w14, w15)
            SB();
            h = Hh[4];  CH(w16, w17, w18, w19)
            h = Hh[5];  CH(w20, w21, w22, w23)
            h = Hh[6];  CH(w24, w25, w26, w27)
            h = Hh[7];  CH(w28, w29, w30, w31)
            SB();
            h = Hh[8];  CH(w32, w33, w34, w35)
            h = Hh[9];  CH(w36, w37, w38, w39)
            h = Hh[10]; CH(w40, w41, w42, w43)
            h = Hh[11]; CH(w44, w45, w46, w47)
            SB();
            h = Hh[12]; CH(w48, w49, w50, w51)
            h = Hh[13]; CH(w52, w53, w54, w55)
            h = Hh[14]; CH(w56, w57, w58, w59)
            h = Hh[15]; MIX_LO(a0, w60, h.x) MIX_HI(a1, w60, h.x)
            h = Hl[0];  CH(u0,  u1,  u2,  u3)
            h = Hl[1];  CH(u4,  u5,  u6,  u7)
            h = Hl[2];  CH(u8,  u9,  u10, u11)
            h = Hl[3];  MIX_LO(a0, u12, h.x) MIX_HI(a1, u12, h.x)
            g2w[tid] = (a0 + a1) + (a2 + a3);
        } else if (is_l1) {
            int tn = t + 1; if (tn >= T_STEPS) tn = T_STEPS - 1;
            const float* xp = x + tn * IN_DIM;
            px01 = pk2h(xp[0], xp[1]); px23 = pk2h(xp[2], xp[3]); px4r = pk2h(xp[4], 0.0f);
        } else if (tid == 510) {
            if (t > 0) out[t - 1] = yp[0] + yp[1] + blin;
        }
        __syncthreads();   // B2: gates2 visible

        // -------- Region 2: h2/c2 act + y reduce  ||  LSTM1 -> h1(t+1) --------
        if (tid < 128) {
            float p = 0.0f;
            if (tid < H2) {
                float gi = g2w[tid];
                float gf = g2w[121 + tid];
                float gg = g2w[242 + tid];
                float go = g2w[363 + tid];
                c2 = fsig(gf) * c2 + fsig(gi) * ftanh(gg);
                float h2n = fsig(go) * ftanh(c2);
                h2f16[tid] = __half_as_ushort(__float2half(h2n));
                p = h2n * wlin;
            }
            #pragma unroll
            for (int off = 32; off >= 1; off >>= 1) p += __shfl_xor(p, off);
            if ((tid & 63) == 0) yp[tid >> 6] = p;
        } else if (is_l1) {
            L1_STEP()
        }
        __syncthreads();   // B3: h2(t), yp, h1(t+1) visible
    }

    if (tid == 510) out[T_STEPS - 1] = yp[0] + yp[1] + blin;
}

extern "C" void kernel_launch(void* const* d_in, const int* in_sizes, int n_in,
                              void* d_out, int out_size, void* d_ws, size_t ws_size,
                              hipStream_t stream) {
    const float* x     = (const float*)d_in[0];
    const float* W_ih1 = (const float*)d_in[1];
    const float* W_hh1 = (const float*)d_in[2];
    const float* b_ih1 = (const float*)d_in[3];
    const float* b_hh1 = (const float*)d_in[4];
    const float* W_ih2 = (const float*)d_in[5];
    const float* W_hh2 = (const float*)d_in[6];
    const float* b_ih2 = (const float*)d_in[7];
    const float* b_hh2 = (const float*)d_in[8];
    const float* W_lin = (const float*)d_in[9];
    const float* b_lin = (const float*)d_in[10];
    const float* h1_0  = (const float*)d_in[11];
    const float* c1_0  = (const float*)d_in[12];
    const float* h2_0  = (const float*)d_in[13];
    const float* c2_0  = (const float*)d_in[14];
    float* out = (float*)d_out;

    hipLaunchKernelGGL(lstm_seq_kernel, dim3(1), dim3(512), 0, stream,
                       x, W_ih1, W_hh1, b_ih1, b_hh1,
                       W_ih2, W_hh2, b_ih2, b_hh2,
                       W_lin, b_lin, h1_0, c1_0, h2_0, c2_0, out);
}